// Round 4
// baseline (499.235 us; speedup 1.0000x reference)
//
#include <hip/hip_runtime.h>

#define SEQ 2048
#define NB 4
#define DIN 768
#define EDIM 768
#define NH 12
#define QKVN 2304
#define QKW 1536
#define SCALE 0.125f
#define PADV -1e9f
#define INV12 (0.0833333333f)
#define ACCW 516   // >= 8*64, stride mod 32 == 4 (quad de-conflict), 16B-aligned rows

typedef unsigned short ushort_t;
typedef __attribute__((ext_vector_type(8))) short bf16x8;
typedef __attribute__((ext_vector_type(4))) float f32x4;

__device__ __forceinline__ ushort_t f2bf(float f) {
    union { float f; unsigned int i; } v; v.f = f;
    unsigned int r = (v.i + 0x7fffu + ((v.i >> 16) & 1u)) >> 16;
    return (ushort_t)r;
}
__device__ __forceinline__ void gl_lds16(const ushort_t* g, ushort_t* l) {
    __builtin_amdgcn_global_load_lds(
        (const __attribute__((address_space(1))) unsigned int*)(g),
        (__attribute__((address_space(3))) unsigned int*)(l),
        16, 0, 0);
}

// ---------------- per-batch window size ----------------
__global__ void wsz_kernel(const int* __restrict__ mask, int* __restrict__ wszp) {
    int b = blockIdx.x;
    __shared__ int cnt;
    if (threadIdx.x == 0) cnt = 0;
    __syncthreads();
    int local = 0;
    for (int s = threadIdx.x; s < SEQ; s += blockDim.x)
        local += (mask[b * SEQ + s] == 0) ? 1 : 0;
    for (int o = 32; o; o >>= 1) local += __shfl_down(local, o, 64);
    if ((threadIdx.x & 63) == 0) atomicAdd(&cnt, local);
    __syncthreads();
    if (threadIdx.x == 0) {
        int len = cnt; if (len > 2048) len = 2048;
        float w = ceilf(((float)len * 10.0f) / 100.0f);
        int wsz = (int)w;
        if (wsz < 2) wsz = 2;
        wszp[b] = wsz;
    }
}

// ---------------- fp32 -> bf16 conversion ----------------
__global__ void cvt_kernel(const float* __restrict__ in, ushort_t* __restrict__ out, int n4) {
    int i = blockIdx.x * blockDim.x + threadIdx.x;
    if (i < n4) {
        float4 f = ((const float4*)in)[i];
        ushort4 u;
        u.x = f2bf(f.x); u.y = f2bf(f.y); u.z = f2bf(f.z); u.w = f2bf(f.w);
        ((ushort4*)out)[i] = u;
    }
}

// ---------------- mmask nonzero-tile flags ----------------
__global__ void flag_kernel(const float* __restrict__ mmask, const int* __restrict__ wszp,
                            int* __restrict__ flags) {
    const int b = blockIdx.z, i16 = blockIdx.y;
    const int wsz = wszp[b];
    const int i0 = i16 * 16;
    const int jt0 = max(0, i0 - wsz) >> 6;
    const int jt1 = min(SEQ - 1, i0 + 15 + wsz) >> 6;
    const int jt = jt0 + blockIdx.x;
    if (jt > jt1) return;
    int any = 0;
    for (int e = threadIdx.x; e < 1024; e += 256) {
        int row = e >> 6, col = e & 63;
        float v = mmask[((size_t)b * SEQ + i0 + row) * SEQ + jt * 64 + col];
        any |= (v != 0.f);
    }
    if (any) flags[(b * 128 + i16) * 32 + jt] = 1;
}

// ---------------- 128x128 bf16 MFMA GEMM ----------------
template<int MODE>
__global__ __launch_bounds__(256) void mfma_gemm128(
    const ushort_t* __restrict__ A, const ushort_t* __restrict__ Bw,
    const float* __restrict__ bias, float* __restrict__ outf,
    ushort_t* __restrict__ qk, ushort_t* __restrict__ vt, int N, int K)
{
    __shared__ __align__(16) ushort_t Al[128 * 64];
    __shared__ __align__(16) ushort_t Bl[128 * 64];
    const int tid  = threadIdx.x;
    const int w    = tid >> 6;
    const int l    = tid & 63;
    const int quad = l >> 4;
    const int lr   = l & 15;
    const int mw   = (w >> 1) * 64;
    const int nw   = (w & 1) * 64;
    const int bm   = blockIdx.y * 128;
    const int bn   = blockIdx.x * 128;
    const int srow = l >> 3;
    const int sg   = (l & 7) ^ srow;

    f32x4 acc[4][4];
    #pragma unroll
    for (int i = 0; i < 4; ++i)
        #pragma unroll
        for (int j = 0; j < 4; ++j)
            #pragma unroll
            for (int r = 0; r < 4; ++r) acc[i][j][r] = 0.f;

    const ushort_t* ga = A  + (size_t)(bm + w * 32 + srow) * K + sg * 8;
    const ushort_t* gb = Bw + (size_t)(bn + w * 32 + srow) * K + sg * 8;
    ushort_t* la = &Al[(w * 32) * 64];
    ushort_t* lb = &Bl[(w * 32) * 64];

    for (int k0 = 0; k0 < K; k0 += 64) {
        __syncthreads();
        #pragma unroll
        for (int i = 0; i < 4; ++i)
            gl_lds16(ga + (size_t)(i * 8) * K + k0, la + i * 8 * 64);
        #pragma unroll
        for (int i = 0; i < 4; ++i)
            gl_lds16(gb + (size_t)(i * 8) * K + k0, lb + i * 8 * 64);
        __syncthreads();
        #pragma unroll
        for (int s = 0; s < 2; ++s) {
            bf16x8 af[4], bf[4];
            #pragma unroll
            for (int t = 0; t < 4; ++t)
                af[t] = *(const bf16x8*)&Al[(mw + t * 16 + lr) * 64 + (((4 * s + quad) ^ (lr & 7)) * 8)];
            #pragma unroll
            for (int t = 0; t < 4; ++t)
                bf[t] = *(const bf16x8*)&Bl[(nw + t * 16 + lr) * 64 + (((4 * s + quad) ^ (lr & 7)) * 8)];
            #pragma unroll
            for (int mt = 0; mt < 4; ++mt)
                #pragma unroll
                for (int nt = 0; nt < 4; ++nt)
                    acc[mt][nt] = __builtin_amdgcn_mfma_f32_16x16x32_bf16(af[mt], bf[nt], acc[mt][nt], 0, 0, 0);
        }
    }

    #pragma unroll
    for (int nt = 0; nt < 4; ++nt) {
        const int gn = bn + nw + nt * 16 + lr;
        const float bv = bias[gn];
        const int hh  = gn / 192;
        const int rem = gn - hh * 192;
        #pragma unroll
        for (int mt = 0; mt < 4; ++mt) {
            const int gm0 = bm + mw + mt * 16 + quad * 4;
            if (MODE == 0) {
                #pragma unroll
                for (int r = 0; r < 4; ++r)
                    outf[(size_t)(gm0 + r) * N + gn] = acc[mt][nt][r] + bv;
            } else if (rem < 128) {
                #pragma unroll
                for (int r = 0; r < 4; ++r)
                    qk[(size_t)(gm0 + r) * QKW + hh * 128 + rem] = f2bf(acc[mt][nt][r] + bv);
            } else {
                // transposed V: 4 consecutive tokens -> one 8B store
                const int bb  = gm0 >> 11;
                const int tok = gm0 & (SEQ - 1);
                ushort4 st;
                st.x = f2bf(acc[mt][nt][0] + bv);
                st.y = f2bf(acc[mt][nt][1] + bv);
                st.z = f2bf(acc[mt][nt][2] + bv);
                st.w = f2bf(acc[mt][nt][3] + bv);
                *(ushort4*)&vt[((size_t)(bb * NH + hh) * 64 + (rem - 128)) * SEQ + tok] = st;
            }
        }
    }
}

// ---------------- fused windowed attention: LDS head-mean accumulator ----------------
// grid (SEQ/16, NB), 256 thr = 4 waves; wave w handles heads {w, w+4, w+8} for the
// same 16 q rows. attn_mean accumulated in LDS, written once (incl. zero fill).
__global__ __launch_bounds__(256) void attn_kernel(
    const ushort_t* __restrict__ qk,    // [NB*SEQ][1536] bf16 (Q|K per head)
    const ushort_t* __restrict__ vt,    // [NB*NH*64][SEQ] bf16 (V transposed)
    const float* __restrict__ mmask,    // [NB][SEQ][SEQ]
    const int* __restrict__ wszp,       // [NB]
    const int* __restrict__ flags,      // [NB][128][32]
    ushort_t* __restrict__ values,      // [NB*SEQ][768] bf16
    float* __restrict__ attn_out)       // [NB][SEQ][SEQ]
{
    __shared__ __align__(16) float accs[16][ACCW];   // 33 KB head-mean accumulator
    __shared__ __align__(16) ushort_t Pb[4][16][72]; // 9.2 KB per-wave P staging
    const int tid  = threadIdx.x;
    const int w    = tid >> 6;
    const int lane = tid & 63;
    const int quad = lane >> 4;
    const int lr   = lane & 15;
    const int b    = blockIdx.y;
    const int iq0  = blockIdx.x * 16;
    const int wsz  = wszp[b];
    const int jlo  = max(0, iq0 - wsz);
    const int jhi  = min(SEQ - 1, iq0 + 15 + wsz);
    const int jt0  = jlo >> 6;
    const int jt1  = jhi >> 6;
    const int nch  = jt1 - jt0 + 1;          // <= 8
    const int jbase = jt0 << 6;
    const int fbase = (b * 128 + blockIdx.x) * 32;

    // zero the accumulator
    for (int i = tid; i < 16 * ACCW / 4; i += 256) ((float4*)accs)[i] = float4{0.f, 0.f, 0.f, 0.f};
    __syncthreads();

    for (int hi = 0; hi < 3; ++hi) {
        const int h = w + hi * 4;
        const ushort_t* qbase = qk + (size_t)(b * SEQ + iq0 + lr) * QKW + h * 128;
        const bf16x8 qf0 = *(const bf16x8*)(qbase + quad * 8);
        const bf16x8 qf1 = *(const bf16x8*)(qbase + 32 + quad * 8);
        const ushort_t* kbase = qk + (size_t)b * SEQ * QKW + h * 128 + 64;
        const ushort_t* vbase = vt + (size_t)(b * NH + h) * 64 * SEQ;

        // ---- pass A: row sums ----
        float lsum[4] = {0.f, 0.f, 0.f, 0.f};
        for (int ci = 0; ci < nch; ++ci) {
            const int jc = jbase + ci * 64;
            f32x4 s4[4];
            #pragma unroll
            for (int t = 0; t < 4; ++t) {
                const ushort_t* kr = kbase + (size_t)(jc + t * 16 + lr) * QKW;
                bf16x8 kf0 = *(const bf16x8*)(kr + quad * 8);
                bf16x8 kf1 = *(const bf16x8*)(kr + 32 + quad * 8);
                #pragma unroll
                for (int r = 0; r < 4; ++r) s4[t][r] = 0.f;
                s4[t] = __builtin_amdgcn_mfma_f32_16x16x32_bf16(qf0, kf0, s4[t], 0, 0, 0);
                s4[t] = __builtin_amdgcn_mfma_f32_16x16x32_bf16(qf1, kf1, s4[t], 0, 0, 0);
            }
            const int anym = flags[fbase + jt0 + ci];
            #pragma unroll
            for (int t = 0; t < 4; ++t) {
                const int gj = jc + t * 16 + lr;
                #pragma unroll
                for (int r = 0; r < 4; ++r) {
                    const int gi = iq0 + quad * 4 + r;
                    float mm = 0.f;
                    if (anym) mm = mmask[((size_t)b * SEQ + gi) * SEQ + gj];
                    const int dist = gi > gj ? gi - gj : gj - gi;
                    const float p = (dist > wsz) ? 0.f : __expf(fmaf(s4[t][r], SCALE, mm));
                    lsum[r] += p;
                }
            }
        }
        #pragma unroll
        for (int r = 0; r < 4; ++r) {
            #pragma unroll
            for (int m = 8; m; m >>= 1) lsum[r] += __shfl_xor(lsum[r], m, 16);
        }
        float invl[4], invl12[4];
        #pragma unroll
        for (int r = 0; r < 4; ++r) { invl[r] = 1.0f / lsum[r]; invl12[r] = invl[r] * INV12; }

        // ---- pass B ----
        f32x4 oacc[4];
        #pragma unroll
        for (int t = 0; t < 4; ++t)
            #pragma unroll
            for (int r = 0; r < 4; ++r) oacc[t][r] = 0.f;

        for (int ci = 0; ci < nch; ++ci) {
            const int jc = jbase + ci * 64;
            f32x4 s4[4];
            #pragma unroll
            for (int t = 0; t < 4; ++t) {
                const ushort_t* kr = kbase + (size_t)(jc + t * 16 + lr) * QKW;
                bf16x8 kf0 = *(const bf16x8*)(kr + quad * 8);
                bf16x8 kf1 = *(const bf16x8*)(kr + 32 + quad * 8);
                #pragma unroll
                for (int r = 0; r < 4; ++r) s4[t][r] = 0.f;
                s4[t] = __builtin_amdgcn_mfma_f32_16x16x32_bf16(qf0, kf0, s4[t], 0, 0, 0);
                s4[t] = __builtin_amdgcn_mfma_f32_16x16x32_bf16(qf1, kf1, s4[t], 0, 0, 0);
            }
            const int anym = flags[fbase + jt0 + ci];
            #pragma unroll
            for (int t = 0; t < 4; ++t) {
                const int gj = jc + t * 16 + lr;
                const int co = jc - jbase + t * 16 + lr;
                #pragma unroll
                for (int r = 0; r < 4; ++r) {
                    const int gi = iq0 + quad * 4 + r;
                    float mm = 0.f;
                    if (anym) mm = mmask[((size_t)b * SEQ + gi) * SEQ + gj];
                    const int dist = gi > gj ? gi - gj : gj - gi;
                    const float p = (dist > wsz) ? 0.f : __expf(fmaf(s4[t][r], SCALE, mm));
                    Pb[w][quad * 4 + r][t * 16 + lr] = f2bf(p);
                    if (p != 0.f)
                        atomicAdd(&accs[quad * 4 + r][co], p * invl12[r]);
                }
            }
            bf16x8 pa0 = *(const bf16x8*)&Pb[w][lr][quad * 8];
            bf16x8 pa1 = *(const bf16x8*)&Pb[w][lr][32 + quad * 8];
            #pragma unroll
            for (int t = 0; t < 4; ++t) {
                const ushort_t* vr = vbase + (size_t)(t * 16 + lr) * SEQ + jc;
                bf16x8 vf0 = *(const bf16x8*)(vr + quad * 8);
                bf16x8 vf1 = *(const bf16x8*)(vr + 32 + quad * 8);
                oacc[t] = __builtin_amdgcn_mfma_f32_16x16x32_bf16(pa0, vf0, oacc[t], 0, 0, 0);
                oacc[t] = __builtin_amdgcn_mfma_f32_16x16x32_bf16(pa1, vf1, oacc[t], 0, 0, 0);
            }
        }
        // values epilogue for this head
        #pragma unroll
        for (int t = 0; t < 4; ++t) {
            #pragma unroll
            for (int r = 0; r < 4; ++r) {
                const int row = iq0 + quad * 4 + r;
                values[(size_t)(b * SEQ + row) * EDIM + h * 64 + t * 16 + lr] =
                    f2bf(oacc[t][r] * invl[r]);
            }
        }
    }
    __syncthreads();

    // ---- write attn_mean: full 2048 cols (zero outside window) ----
    {
        const int irow = tid >> 4;
        const int c16  = tid & 15;
        const int span = nch * 64;
        float* dst = attn_out + ((size_t)(b * SEQ) + iq0 + irow) * SEQ;
        for (int j4 = c16; j4 < SEQ / 4; j4 += 16) {
            const int j = j4 * 4;
            const int o = j - jbase;
            float4 v = {0.f, 0.f, 0.f, 0.f};
            if (o >= 0 && o + 3 < span) {
                v = *(const float4*)&accs[irow][o];
            } else if (o + 3 >= 0 && o < span) {
                v.x = (o + 0 >= 0 && o + 0 < span) ? accs[irow][o + 0] : 0.f;
                v.y = (o + 1 >= 0 && o + 1 < span) ? accs[irow][o + 1] : 0.f;
                v.z = (o + 2 >= 0 && o + 2 < span) ? accs[irow][o + 2] : 0.f;
                v.w = (o + 3 >= 0 && o + 3 < span) ? accs[irow][o + 3] : 0.f;
            }
            *(float4*)&dst[j] = v;
        }
    }
}

extern "C" void kernel_launch(void* const* d_in, const int* in_sizes, int n_in,
                              void* d_out, int out_size, void* d_ws, size_t ws_size,
                              hipStream_t stream) {
    const float* x      = (const float*)d_in[0];
    const int*   pad    = (const int*)d_in[1];
    const float* mmask  = (const float*)d_in[2];
    const float* qkv_w  = (const float*)d_in[3];
    const float* qkv_b  = (const float*)d_in[4];
    const float* o_w    = (const float*)d_in[5];
    const float* o_b    = (const float*)d_in[6];

    float* out_o    = (float*)d_out;
    float* out_attn = out_o + (size_t)NB * SEQ * EDIM;

    ushort_t* qk     = (ushort_t*)d_ws;                       // NB*SEQ*1536
    ushort_t* vt     = qk + (size_t)NB * SEQ * QKW;           // NB*NH*64*SEQ
    ushort_t* xb     = vt + (size_t)NB * NH * 64 * SEQ;       // x bf16
    ushort_t* values = xb;                                    // alias (after GEMM1)
    ushort_t* wqkvb  = xb + (size_t)NB * SEQ * DIN;
    ushort_t* wob    = wqkvb + (size_t)QKVN * DIN;
    int*      wszp   = (int*)(wob + (size_t)EDIM * EDIM);
    int*      flags  = wszp + 4;

    hipMemsetAsync(flags, 0, (size_t)NB * 128 * 32 * sizeof(int), stream);

    wsz_kernel<<<NB, 256, 0, stream>>>(pad, wszp);
    flag_kernel<<<dim3(8, 128, NB), 256, 0, stream>>>(mmask, wszp, flags);

    const int nx = NB * SEQ * DIN / 4, nw1 = QKVN * DIN / 4, nw2 = EDIM * EDIM / 4;
    cvt_kernel<<<(nx  + 255) / 256, 256, 0, stream>>>(x,     xb,    nx);
    cvt_kernel<<<(nw1 + 255) / 256, 256, 0, stream>>>(qkv_w, wqkvb, nw1);
    cvt_kernel<<<(nw2 + 255) / 256, 256, 0, stream>>>(o_w,   wob,   nw2);

    mfma_gemm128<1><<<dim3(QKVN / 128, (NB * SEQ) / 128), 256, 0, stream>>>(
        xb, wqkvb, qkv_b, nullptr, qk, vt, QKVN, DIN);

    attn_kernel<<<dim3(SEQ / 16, NB), 256, 0, stream>>>(
        qk, vt, mmask, wszp, flags, values, out_attn);

    mfma_gemm128<0><<<dim3(EDIM / 128, (NB * SEQ) / 128), 256, 0, stream>>>(
        values, wob, o_b, out_o, nullptr, nullptr, EDIM, EDIM);
}

// Round 5
// 372.242 us; speedup vs baseline: 1.3412x; 1.3412x over previous
//
#include <hip/hip_runtime.h>

#define SEQ 2048
#define NB 4
#define DIN 768
#define EDIM 768
#define NH 12
#define QKVN 2304
#define QKW 1536
#define SCALE 0.125f
#define PADV -1e9f
#define INV12 (0.0833333333f)
#define PSW 520   // Ps row stride in elems: even (16B-align ok), 520*2/4=260 words, 260%32=4

typedef unsigned short ushort_t;
typedef __attribute__((ext_vector_type(8))) short bf16x8;
typedef __attribute__((ext_vector_type(4))) float f32x4;

__device__ __forceinline__ float bf2f(ushort_t u) {
    union { unsigned int i; float f; } v; v.i = ((unsigned int)u) << 16; return v.f;
}
__device__ __forceinline__ ushort_t f2bf(float f) {
    union { float f; unsigned int i; } v; v.f = f;
    unsigned int r = (v.i + 0x7fffu + ((v.i >> 16) & 1u)) >> 16;
    return (ushort_t)r;
}
__device__ __forceinline__ void gl_lds16(const ushort_t* g, ushort_t* l) {
    __builtin_amdgcn_global_load_lds(
        (const __attribute__((address_space(1))) unsigned int*)(g),
        (__attribute__((address_space(3))) unsigned int*)(l),
        16, 0, 0);
}

// ---------------- per-batch window size ----------------
__global__ void wsz_kernel(const int* __restrict__ mask, int* __restrict__ wszp) {
    int b = blockIdx.x;
    __shared__ int cnt;
    if (threadIdx.x == 0) cnt = 0;
    __syncthreads();
    int local = 0;
    for (int s = threadIdx.x; s < SEQ; s += blockDim.x)
        local += (mask[b * SEQ + s] == 0) ? 1 : 0;
    for (int o = 32; o; o >>= 1) local += __shfl_down(local, o, 64);
    if ((threadIdx.x & 63) == 0) atomicAdd(&cnt, local);
    __syncthreads();
    if (threadIdx.x == 0) {
        int len = cnt; if (len > 2048) len = 2048;
        float w = ceilf(((float)len * 10.0f) / 100.0f);
        int wsz = (int)w;
        if (wsz < 2) wsz = 2;
        wszp[b] = wsz;
    }
}

// ---------------- fp32 -> bf16 conversion ----------------
__global__ void cvt_kernel(const float* __restrict__ in, ushort_t* __restrict__ out, int n4) {
    int i = blockIdx.x * blockDim.x + threadIdx.x;
    if (i < n4) {
        float4 f = ((const float4*)in)[i];
        ushort4 u;
        u.x = f2bf(f.x); u.y = f2bf(f.y); u.z = f2bf(f.z); u.w = f2bf(f.w);
        ((ushort4*)out)[i] = u;
    }
}

// ---------------- mmask nonzero-tile flags ----------------
__global__ void flag_kernel(const float* __restrict__ mmask, const int* __restrict__ wszp,
                            int* __restrict__ flags) {
    const int b = blockIdx.z, i16 = blockIdx.y;
    const int wsz = wszp[b];
    const int i0 = i16 * 16;
    const int jt0 = max(0, i0 - wsz) >> 6;
    const int jt1 = min(SEQ - 1, i0 + 15 + wsz) >> 6;
    const int jt = jt0 + blockIdx.x;
    if (jt > jt1) return;
    int any = 0;
    for (int e = threadIdx.x; e < 1024; e += 256) {
        int row = e >> 6, col = e & 63;
        float v = mmask[((size_t)b * SEQ + i0 + row) * SEQ + jt * 64 + col];
        any |= (v != 0.f);
    }
    if (any) flags[(b * 128 + i16) * 32 + jt] = 1;
}

// ---------------- 128x128 bf16 MFMA GEMM ----------------
template<int MODE>
__global__ __launch_bounds__(256) void mfma_gemm128(
    const ushort_t* __restrict__ A, const ushort_t* __restrict__ Bw,
    const float* __restrict__ bias, float* __restrict__ outf,
    ushort_t* __restrict__ qk, ushort_t* __restrict__ vt, int N, int K)
{
    __shared__ __align__(16) ushort_t Al[128 * 64];
    __shared__ __align__(16) ushort_t Bl[128 * 64];
    const int tid  = threadIdx.x;
    const int w    = tid >> 6;
    const int l    = tid & 63;
    const int quad = l >> 4;
    const int lr   = l & 15;
    const int mw   = (w >> 1) * 64;
    const int nw   = (w & 1) * 64;
    const int bm   = blockIdx.y * 128;
    const int bn   = blockIdx.x * 128;
    const int srow = l >> 3;
    const int sg   = (l & 7) ^ srow;

    f32x4 acc[4][4];
    #pragma unroll
    for (int i = 0; i < 4; ++i)
        #pragma unroll
        for (int j = 0; j < 4; ++j)
            #pragma unroll
            for (int r = 0; r < 4; ++r) acc[i][j][r] = 0.f;

    const ushort_t* ga = A  + (size_t)(bm + w * 32 + srow) * K + sg * 8;
    const ushort_t* gb = Bw + (size_t)(bn + w * 32 + srow) * K + sg * 8;
    ushort_t* la = &Al[(w * 32) * 64];
    ushort_t* lb = &Bl[(w * 32) * 64];

    for (int k0 = 0; k0 < K; k0 += 64) {
        __syncthreads();
        #pragma unroll
        for (int i = 0; i < 4; ++i)
            gl_lds16(ga + (size_t)(i * 8) * K + k0, la + i * 8 * 64);
        #pragma unroll
        for (int i = 0; i < 4; ++i)
            gl_lds16(gb + (size_t)(i * 8) * K + k0, lb + i * 8 * 64);
        __syncthreads();
        #pragma unroll
        for (int s = 0; s < 2; ++s) {
            bf16x8 af[4], bf[4];
            #pragma unroll
            for (int t = 0; t < 4; ++t)
                af[t] = *(const bf16x8*)&Al[(mw + t * 16 + lr) * 64 + (((4 * s + quad) ^ (lr & 7)) * 8)];
            #pragma unroll
            for (int t = 0; t < 4; ++t)
                bf[t] = *(const bf16x8*)&Bl[(nw + t * 16 + lr) * 64 + (((4 * s + quad) ^ (lr & 7)) * 8)];
            #pragma unroll
            for (int mt = 0; mt < 4; ++mt)
                #pragma unroll
                for (int nt = 0; nt < 4; ++nt)
                    acc[mt][nt] = __builtin_amdgcn_mfma_f32_16x16x32_bf16(af[mt], bf[nt], acc[mt][nt], 0, 0, 0);
        }
    }

    #pragma unroll
    for (int nt = 0; nt < 4; ++nt) {
        const int gn = bn + nw + nt * 16 + lr;
        const float bv = bias[gn];
        const int hh  = gn / 192;
        const int rem = gn - hh * 192;
        #pragma unroll
        for (int mt = 0; mt < 4; ++mt) {
            const int gm0 = bm + mw + mt * 16 + quad * 4;
            if (MODE == 0) {
                #pragma unroll
                for (int r = 0; r < 4; ++r)
                    outf[(size_t)(gm0 + r) * N + gn] = acc[mt][nt][r] + bv;
            } else if (rem < 128) {
                #pragma unroll
                for (int r = 0; r < 4; ++r)
                    qk[(size_t)(gm0 + r) * QKW + hh * 128 + rem] = f2bf(acc[mt][nt][r] + bv);
            } else {
                const int bb  = gm0 >> 11;
                const int tok = gm0 & (SEQ - 1);
                ushort4 st;
                st.x = f2bf(acc[mt][nt][0] + bv);
                st.y = f2bf(acc[mt][nt][1] + bv);
                st.z = f2bf(acc[mt][nt][2] + bv);
                st.w = f2bf(acc[mt][nt][3] + bv);
                *(ushort4*)&vt[((size_t)(bb * NH + hh) * 64 + (rem - 128)) * SEQ + tok] = st;
            }
        }
    }
}

// ---------------- fused windowed attention v3 ----------------
// 1D grid of 512 blocks, XCD-swizzled: lin -> (b = (lin>>1)&3, s = lin&1,
// i16 = (lin>>3) + 64*s). All 4 waves cooperate on one head at a time:
// single QK pass -> Ps (bf16, LDS) -> register head-mean accum + per-wave PV.
__global__ __launch_bounds__(256) void attn_kernel(
    const ushort_t* __restrict__ qk,    // [NB*SEQ][1536] bf16 (Q|K per head)
    const ushort_t* __restrict__ vt,    // [NB*NH*64][SEQ] bf16 (V transposed)
    const float* __restrict__ mmask,    // [NB][SEQ][SEQ]
    const int* __restrict__ wszp,       // [NB]
    const int* __restrict__ flags,      // [NB][128][32]
    ushort_t* __restrict__ values,      // [NB*SEQ][768] bf16
    float* __restrict__ attn_out)       // [NB][SEQ][SEQ]
{
    __shared__ __align__(16) ushort_t Ps[16 * PSW];  // 16.6 KB: exp(QK) tile, bf16
    __shared__ float lsump[4][16];                   // per-wave row-sum partials
    const int tid  = threadIdx.x;
    const int w    = tid >> 6;
    const int lane = tid & 63;
    const int quad = lane >> 4;
    const int lr   = lane & 15;

    const int lin  = blockIdx.x;
    const int s    = lin & 1;
    const int b    = (lin >> 1) & 3;
    const int i16  = (lin >> 3) + 64 * s;
    const int iq0  = i16 * 16;

    const int wsz  = wszp[b];
    const int jlo  = max(0, iq0 - wsz);
    const int jhi  = min(SEQ - 1, iq0 + 15 + wsz);
    const int jt0  = jlo >> 6;
    const int nch  = (jhi >> 6) - jt0 + 1;   // <= 8
    const int jbase = jt0 << 6;
    const int span  = nch << 6;              // <= 512
    const int fbase = (b * 128 + i16) * 32;

    // mean-accum ownership: row = tid&15, col-group cg = tid>>4 (32 cols each)
    const int arow = tid & 15;
    const int acg  = tid >> 4;
    float acc[32];
    #pragma unroll
    for (int k = 0; k < 32; ++k) acc[k] = 0.f;

    const ushort_t* kbase = qk + (size_t)b * SEQ * QKW + 64;
    const ushort_t* vhead = vt + (size_t)b * NH * 64 * SEQ;

    for (int h = 0; h < NH; ++h) {
        const int hq = h * 128;
        const ushort_t* qbase = qk + (size_t)(b * SEQ + iq0 + lr) * QKW + hq;
        const bf16x8 qf0 = *(const bf16x8*)(qbase + quad * 8);
        const bf16x8 qf1 = *(const bf16x8*)(qbase + 32 + quad * 8);

        // ---- QK + exp for this wave's chunks (ci = w, w+4) ----
        float ls[4] = {0.f, 0.f, 0.f, 0.f};
        #pragma unroll
        for (int cc = 0; cc < 2; ++cc) {
            const int ci = w + cc * 4;
            if (ci < nch) {
                const int jc = jbase + ci * 64;
                f32x4 s4[4];
                #pragma unroll
                for (int t = 0; t < 4; ++t) {
                    const ushort_t* kr = kbase + (size_t)(jc + t * 16 + lr) * QKW + hq;
                    bf16x8 kf0 = *(const bf16x8*)(kr + quad * 8);
                    bf16x8 kf1 = *(const bf16x8*)(kr + 32 + quad * 8);
                    #pragma unroll
                    for (int r = 0; r < 4; ++r) s4[t][r] = 0.f;
                    s4[t] = __builtin_amdgcn_mfma_f32_16x16x32_bf16(qf0, kf0, s4[t], 0, 0, 0);
                    s4[t] = __builtin_amdgcn_mfma_f32_16x16x32_bf16(qf1, kf1, s4[t], 0, 0, 0);
                }
                const int anym = flags[fbase + jt0 + ci];
                #pragma unroll
                for (int t = 0; t < 4; ++t) {
                    const int gj = jc + t * 16 + lr;
                    #pragma unroll
                    for (int r = 0; r < 4; ++r) {
                        const int gi = iq0 + quad * 4 + r;
                        float mm = 0.f;
                        if (anym) mm = mmask[((size_t)b * SEQ + gi) * SEQ + gj];
                        const int dist = gi > gj ? gi - gj : gj - gi;
                        const float p = (dist > wsz) ? 0.f : __expf(fmaf(s4[t][r], SCALE, mm));
                        ls[r] += p;
                        Ps[(quad * 4 + r) * PSW + (ci * 64 + t * 16 + lr)] = f2bf(p);
                    }
                }
            }
        }
        // wave-level row sums (16-lane groups share a row set)
        #pragma unroll
        for (int r = 0; r < 4; ++r) {
            #pragma unroll
            for (int m = 8; m; m >>= 1) ls[r] += __shfl_xor(ls[r], m, 16);
        }
        if (lr == 0) {
            #pragma unroll
            for (int r = 0; r < 4; ++r) lsump[w][quad * 4 + r] = ls[r];
        }
        __syncthreads();

        // ---- head-mean accumulation into registers ----
        if (acg * 32 < span) {
            const float lrow = lsump[0][arow] + lsump[1][arow] + lsump[2][arow] + lsump[3][arow];
            const float sc = INV12 / lrow;
            const ushort_t* prow = &Ps[arow * PSW + acg * 32];
            #pragma unroll
            for (int k = 0; k < 8; ++k) {
                ushort4 u = *(const ushort4*)(prow + k * 4);
                acc[k * 4 + 0] = fmaf(bf2f(u.x), sc, acc[k * 4 + 0]);
                acc[k * 4 + 1] = fmaf(bf2f(u.y), sc, acc[k * 4 + 1]);
                acc[k * 4 + 2] = fmaf(bf2f(u.z), sc, acc[k * 4 + 2]);
                acc[k * 4 + 3] = fmaf(bf2f(u.w), sc, acc[k * 4 + 3]);
            }
        }

        // ---- PV: wave w computes d-slice [w*16, w*16+16) over all chunks ----
        {
            f32x4 oacc;
            #pragma unroll
            for (int r = 0; r < 4; ++r) oacc[r] = 0.f;
            const ushort_t* vrow = vhead + (size_t)(h * 64 + w * 16 + lr) * SEQ + jbase;
            for (int ci = 0; ci < nch; ++ci) {
                const int tok0 = ci * 64;
                #pragma unroll
                for (int s2 = 0; s2 < 2; ++s2) {
                    bf16x8 pa = *(const bf16x8*)&Ps[lr * PSW + tok0 + s2 * 32 + quad * 8];
                    bf16x8 vf = *(const bf16x8*)(vrow + tok0 + s2 * 32 + quad * 8);
                    oacc = __builtin_amdgcn_mfma_f32_16x16x32_bf16(pa, vf, oacc, 0, 0, 0);
                }
            }
            float4 lq = *(const float4*)&lsump[0][quad * 4];
            float4 l1 = *(const float4*)&lsump[1][quad * 4];
            float4 l2 = *(const float4*)&lsump[2][quad * 4];
            float4 l3 = *(const float4*)&lsump[3][quad * 4];
            float lr4[4] = { lq.x + l1.x + l2.x + l3.x, lq.y + l1.y + l2.y + l3.y,
                             lq.z + l1.z + l2.z + l3.z, lq.w + l1.w + l2.w + l3.w };
            #pragma unroll
            for (int r = 0; r < 4; ++r) {
                const int row = iq0 + quad * 4 + r;
                values[(size_t)(b * SEQ + row) * EDIM + h * 64 + w * 16 + lr] =
                    f2bf(oacc[r] / lr4[r]);
            }
        }
        __syncthreads();   // Ps/lsump reuse next head
    }

    // ---- write attn_mean ----
    // in-window: owners write their 32 accumulated cols
    if (acg * 32 < span) {
        float* dst = attn_out + ((size_t)b * SEQ + iq0 + arow) * SEQ + jbase + acg * 32;
        #pragma unroll
        for (int k = 0; k < 8; ++k) {
            float4 v = { acc[k * 4 + 0], acc[k * 4 + 1], acc[k * 4 + 2], acc[k * 4 + 3] };
            *(float4*)(dst + k * 4) = v;
        }
    }
    // outside window: coalesced zero fill
    {
        const int c4lo = jbase >> 2;
        const int c4hi = (jbase + span) >> 2;
        const float4 z = {0.f, 0.f, 0.f, 0.f};
        for (int f = tid; f < 16 * 512; f += 256) {
            const int i  = f >> 9;
            const int c4 = f & 511;
            if (c4 < c4lo || c4 >= c4hi)
                *(float4*)(attn_out + ((size_t)b * SEQ + iq0 + i) * SEQ + c4 * 4) = z;
        }
    }
}

extern "C" void kernel_launch(void* const* d_in, const int* in_sizes, int n_in,
                              void* d_out, int out_size, void* d_ws, size_t ws_size,
                              hipStream_t stream) {
    const float* x      = (const float*)d_in[0];
    const int*   pad    = (const int*)d_in[1];
    const float* mmask  = (const float*)d_in[2];
    const float* qkv_w  = (const float*)d_in[3];
    const float* qkv_b  = (const float*)d_in[4];
    const float* o_w    = (const float*)d_in[5];
    const float* o_b    = (const float*)d_in[6];

    float* out_o    = (float*)d_out;
    float* out_attn = out_o + (size_t)NB * SEQ * EDIM;

    ushort_t* qk     = (ushort_t*)d_ws;                       // NB*SEQ*1536
    ushort_t* vt     = qk + (size_t)NB * SEQ * QKW;           // NB*NH*64*SEQ
    ushort_t* xb     = vt + (size_t)NB * NH * 64 * SEQ;       // x bf16
    ushort_t* values = xb;                                    // alias (after GEMM1)
    ushort_t* wqkvb  = xb + (size_t)NB * SEQ * DIN;
    ushort_t* wob    = wqkvb + (size_t)QKVN * DIN;
    int*      wszp   = (int*)(wob + (size_t)EDIM * EDIM);
    int*      flags  = wszp + 4;

    hipMemsetAsync(flags, 0, (size_t)NB * 128 * 32 * sizeof(int), stream);

    wsz_kernel<<<NB, 256, 0, stream>>>(pad, wszp);
    flag_kernel<<<dim3(8, 128, NB), 256, 0, stream>>>(mmask, wszp, flags);

    const int nx = NB * SEQ * DIN / 4, nw1 = QKVN * DIN / 4, nw2 = EDIM * EDIM / 4;
    cvt_kernel<<<(nx  + 255) / 256, 256, 0, stream>>>(x,     xb,    nx);
    cvt_kernel<<<(nw1 + 255) / 256, 256, 0, stream>>>(qkv_w, wqkvb, nw1);
    cvt_kernel<<<(nw2 + 255) / 256, 256, 0, stream>>>(o_w,   wob,   nw2);

    mfma_gemm128<1><<<dim3(QKVN / 128, (NB * SEQ) / 128), 256, 0, stream>>>(
        xb, wqkvb, qkv_b, nullptr, qk, vt, QKVN, DIN);

    attn_kernel<<<512, 256, 0, stream>>>(
        qk, vt, mmask, wszp, flags, values, out_attn);

    mfma_gemm128<0><<<dim3(EDIM / 128, (NB * SEQ) / 128), 256, 0, stream>>>(
        values, wob, o_b, out_o, nullptr, nullptr, EDIM, EDIM);
}

// Round 6
// 345.128 us; speedup vs baseline: 1.4465x; 1.0786x over previous
//
#include <hip/hip_runtime.h>

#define SEQ 2048
#define NB 4
#define DIN 768
#define EDIM 768
#define NH 12
#define QKVN 2304
#define QKW 1536
#define SCALE 0.125f
#define PADV -1e9f
#define INV12 (0.0833333333f)
#define PSW 520   // Ps row stride in elems

typedef unsigned short ushort_t;
typedef __attribute__((ext_vector_type(8))) short bf16x8;
typedef __attribute__((ext_vector_type(4))) float f32x4;

__device__ __forceinline__ float bf2f(ushort_t u) {
    union { unsigned int i; float f; } v; v.i = ((unsigned int)u) << 16; return v.f;
}
__device__ __forceinline__ ushort_t f2bf(float f) {
    union { float f; unsigned int i; } v; v.f = f;
    unsigned int r = (v.i + 0x7fffu + ((v.i >> 16) & 1u)) >> 16;
    return (ushort_t)r;
}
__device__ __forceinline__ void gl_lds16(const ushort_t* g, ushort_t* l) {
    __builtin_amdgcn_global_load_lds(
        (const __attribute__((address_space(1))) unsigned int*)(g),
        (__attribute__((address_space(3))) unsigned int*)(l),
        16, 0, 0);
}

// ---------------- per-batch window size ----------------
__global__ void wsz_kernel(const int* __restrict__ mask, int* __restrict__ wszp) {
    int b = blockIdx.x;
    __shared__ int cnt;
    if (threadIdx.x == 0) cnt = 0;
    __syncthreads();
    int local = 0;
    for (int s = threadIdx.x; s < SEQ; s += blockDim.x)
        local += (mask[b * SEQ + s] == 0) ? 1 : 0;
    for (int o = 32; o; o >>= 1) local += __shfl_down(local, o, 64);
    if ((threadIdx.x & 63) == 0) atomicAdd(&cnt, local);
    __syncthreads();
    if (threadIdx.x == 0) {
        int len = cnt; if (len > 2048) len = 2048;
        float w = ceilf(((float)len * 10.0f) / 100.0f);
        int wsz = (int)w;
        if (wsz < 2) wsz = 2;
        wszp[b] = wsz;
    }
}

// ---------------- fp32 -> bf16 conversion ----------------
__global__ void cvt_kernel(const float* __restrict__ in, ushort_t* __restrict__ out, int n4) {
    int i = blockIdx.x * blockDim.x + threadIdx.x;
    if (i < n4) {
        float4 f = ((const float4*)in)[i];
        ushort4 u;
        u.x = f2bf(f.x); u.y = f2bf(f.y); u.z = f2bf(f.z); u.w = f2bf(f.w);
        ((ushort4*)out)[i] = u;
    }
}

// ---------------- mmask nonzero-tile flags ----------------
__global__ void flag_kernel(const float* __restrict__ mmask, const int* __restrict__ wszp,
                            int* __restrict__ flags) {
    const int b = blockIdx.z, i16 = blockIdx.y;
    const int wsz = wszp[b];
    const int i0 = i16 * 16;
    const int jt0 = max(0, i0 - wsz) >> 6;
    const int jt1 = min(SEQ - 1, i0 + 15 + wsz) >> 6;
    const int jt = jt0 + blockIdx.x;
    if (jt > jt1) return;
    int any = 0;
    for (int e = threadIdx.x; e < 1024; e += 256) {
        int row = e >> 6, col = e & 63;
        float v = mmask[((size_t)b * SEQ + i0 + row) * SEQ + jt * 64 + col];
        any |= (v != 0.f);
    }
    if (any) flags[(b * 128 + i16) * 32 + jt] = 1;
}

// ---------------- 128x128 bf16 MFMA GEMM ----------------
template<int MODE>
__global__ __launch_bounds__(256) void mfma_gemm128(
    const ushort_t* __restrict__ A, const ushort_t* __restrict__ Bw,
    const float* __restrict__ bias, float* __restrict__ outf,
    ushort_t* __restrict__ qk, ushort_t* __restrict__ vt, int N, int K)
{
    __shared__ __align__(16) ushort_t Al[128 * 64];
    __shared__ __align__(16) ushort_t Bl[128 * 64];
    const int tid  = threadIdx.x;
    const int w    = tid >> 6;
    const int l    = tid & 63;
    const int quad = l >> 4;
    const int lr   = l & 15;
    const int mw   = (w >> 1) * 64;
    const int nw   = (w & 1) * 64;
    const int bm   = blockIdx.y * 128;
    const int bn   = blockIdx.x * 128;
    const int srow = l >> 3;
    const int sg   = (l & 7) ^ srow;

    f32x4 acc[4][4];
    #pragma unroll
    for (int i = 0; i < 4; ++i)
        #pragma unroll
        for (int j = 0; j < 4; ++j)
            #pragma unroll
            for (int r = 0; r < 4; ++r) acc[i][j][r] = 0.f;

    const ushort_t* ga = A  + (size_t)(bm + w * 32 + srow) * K + sg * 8;
    const ushort_t* gb = Bw + (size_t)(bn + w * 32 + srow) * K + sg * 8;
    ushort_t* la = &Al[(w * 32) * 64];
    ushort_t* lb = &Bl[(w * 32) * 64];

    for (int k0 = 0; k0 < K; k0 += 64) {
        __syncthreads();
        #pragma unroll
        for (int i = 0; i < 4; ++i)
            gl_lds16(ga + (size_t)(i * 8) * K + k0, la + i * 8 * 64);
        #pragma unroll
        for (int i = 0; i < 4; ++i)
            gl_lds16(gb + (size_t)(i * 8) * K + k0, lb + i * 8 * 64);
        __syncthreads();
        #pragma unroll
        for (int s = 0; s < 2; ++s) {
            bf16x8 af[4], bf[4];
            #pragma unroll
            for (int t = 0; t < 4; ++t)
                af[t] = *(const bf16x8*)&Al[(mw + t * 16 + lr) * 64 + (((4 * s + quad) ^ (lr & 7)) * 8)];
            #pragma unroll
            for (int t = 0; t < 4; ++t)
                bf[t] = *(const bf16x8*)&Bl[(nw + t * 16 + lr) * 64 + (((4 * s + quad) ^ (lr & 7)) * 8)];
            #pragma unroll
            for (int mt = 0; mt < 4; ++mt)
                #pragma unroll
                for (int nt = 0; nt < 4; ++nt)
                    acc[mt][nt] = __builtin_amdgcn_mfma_f32_16x16x32_bf16(af[mt], bf[nt], acc[mt][nt], 0, 0, 0);
        }
    }

    #pragma unroll
    for (int nt = 0; nt < 4; ++nt) {
        const int gn = bn + nw + nt * 16 + lr;
        const float bv = bias[gn];
        const int hh  = gn / 192;
        const int rem = gn - hh * 192;
        #pragma unroll
        for (int mt = 0; mt < 4; ++mt) {
            const int gm0 = bm + mw + mt * 16 + quad * 4;
            if (MODE == 0) {
                #pragma unroll
                for (int r = 0; r < 4; ++r)
                    outf[(size_t)(gm0 + r) * N + gn] = acc[mt][nt][r] + bv;
            } else if (rem < 128) {
                #pragma unroll
                for (int r = 0; r < 4; ++r)
                    qk[(size_t)(gm0 + r) * QKW + hh * 128 + rem] = f2bf(acc[mt][nt][r] + bv);
            } else {
                const int bb  = gm0 >> 11;
                const int tok = gm0 & (SEQ - 1);
                ushort4 st;
                st.x = f2bf(acc[mt][nt][0] + bv);
                st.y = f2bf(acc[mt][nt][1] + bv);
                st.z = f2bf(acc[mt][nt][2] + bv);
                st.w = f2bf(acc[mt][nt][3] + bv);
                *(ushort4*)&vt[((size_t)(bb * NH + hh) * 64 + (rem - 128)) * SEQ + tok] = st;
            }
        }
    }
}

// ---------------- fused windowed attention v4: 512 thr, 2 heads concurrent ----------------
// 1D grid of 512 blocks, XCD-swizzled. Waves 0-3 -> even head, 4-7 -> odd head of
// each pair; per-head code identical to v3 with double-buffered Ps/lsump.
__global__ __launch_bounds__(512) void attn_kernel(
    const ushort_t* __restrict__ qk,    // [NB*SEQ][1536] bf16 (Q|K per head)
    const ushort_t* __restrict__ vt,    // [NB*NH*64][SEQ] bf16 (V transposed)
    const float* __restrict__ mmask,    // [NB][SEQ][SEQ]
    const int* __restrict__ wszp,       // [NB]
    const int* __restrict__ flags,      // [NB][128][32]
    ushort_t* __restrict__ values,      // [NB*SEQ][768] bf16
    float* __restrict__ attn_out)       // [NB][SEQ][SEQ]
{
    __shared__ __align__(16) ushort_t Ps[2][16 * PSW];  // 33.3 KB
    __shared__ float lsump[2][4][16];
    const int tid  = threadIdx.x;
    const int w    = tid >> 6;       // 0..7
    const int hg   = w >> 2;         // head-group 0/1
    const int ww   = w & 3;          // wave within head
    const int lane = tid & 63;
    const int quad = lane >> 4;
    const int lr   = lane & 15;

    const int lin  = blockIdx.x;
    const int s    = lin & 1;
    const int b    = (lin >> 1) & 3;
    const int i16  = (lin >> 3) + 64 * s;
    const int iq0  = i16 * 16;

    const int wsz  = wszp[b];
    const int jlo  = max(0, iq0 - wsz);
    const int jhi  = min(SEQ - 1, iq0 + 15 + wsz);
    const int jt0  = jlo >> 6;
    const int nch  = (jhi >> 6) - jt0 + 1;   // <= 8
    const int jbase = jt0 << 6;
    const int span  = nch << 6;              // <= 512
    const int fbase = (b * 128 + i16) * 32;

    // mean-accum ownership: row = tid&15, col-group = tid>>4 (16 cols each, 32 groups)
    const int arow = tid & 15;
    const int acg  = tid >> 4;
    float acc[16];
    #pragma unroll
    for (int k = 0; k < 16; ++k) acc[k] = 0.f;

    const ushort_t* kbase = qk + (size_t)b * SEQ * QKW + 64;
    const ushort_t* vhead = vt + (size_t)b * NH * 64 * SEQ;

    for (int hp = 0; hp < NH / 2; ++hp) {
        const int h  = hp * 2 + hg;
        const int hq = h * 128;
        const ushort_t* qbase = qk + (size_t)(b * SEQ + iq0 + lr) * QKW + hq;
        const bf16x8 qf0 = *(const bf16x8*)(qbase + quad * 8);
        const bf16x8 qf1 = *(const bf16x8*)(qbase + 32 + quad * 8);

        // ---- QK + exp for this wave's chunks (ci = ww, ww+4) ----
        float ls[4] = {0.f, 0.f, 0.f, 0.f};
        #pragma unroll
        for (int cc = 0; cc < 2; ++cc) {
            const int ci = ww + cc * 4;
            if (ci < nch) {
                const int jc = jbase + ci * 64;
                f32x4 s4[4];
                #pragma unroll
                for (int t = 0; t < 4; ++t) {
                    const ushort_t* kr = kbase + (size_t)(jc + t * 16 + lr) * QKW + hq;
                    bf16x8 kf0 = *(const bf16x8*)(kr + quad * 8);
                    bf16x8 kf1 = *(const bf16x8*)(kr + 32 + quad * 8);
                    #pragma unroll
                    for (int r = 0; r < 4; ++r) s4[t][r] = 0.f;
                    s4[t] = __builtin_amdgcn_mfma_f32_16x16x32_bf16(qf0, kf0, s4[t], 0, 0, 0);
                    s4[t] = __builtin_amdgcn_mfma_f32_16x16x32_bf16(qf1, kf1, s4[t], 0, 0, 0);
                }
                const int anym = flags[fbase + jt0 + ci];
                #pragma unroll
                for (int t = 0; t < 4; ++t) {
                    const int gj = jc + t * 16 + lr;
                    #pragma unroll
                    for (int r = 0; r < 4; ++r) {
                        const int gi = iq0 + quad * 4 + r;
                        float mm = 0.f;
                        if (anym) mm = mmask[((size_t)b * SEQ + gi) * SEQ + gj];
                        const int dist = gi > gj ? gi - gj : gj - gi;
                        const float p = (dist > wsz) ? 0.f : __expf(fmaf(s4[t][r], SCALE, mm));
                        ls[r] += p;
                        Ps[hg][(quad * 4 + r) * PSW + (ci * 64 + t * 16 + lr)] = f2bf(p);
                    }
                }
            }
        }
        #pragma unroll
        for (int r = 0; r < 4; ++r) {
            #pragma unroll
            for (int m = 8; m; m >>= 1) ls[r] += __shfl_xor(ls[r], m, 16);
        }
        if (lr == 0) {
            #pragma unroll
            for (int r = 0; r < 4; ++r) lsump[hg][ww][quad * 4 + r] = ls[r];
        }
        __syncthreads();

        // ---- head-mean accumulation into registers (both heads of the pair) ----
        if (acg * 16 < span) {
            const float l0 = lsump[0][0][arow] + lsump[0][1][arow] + lsump[0][2][arow] + lsump[0][3][arow];
            const float l1 = lsump[1][0][arow] + lsump[1][1][arow] + lsump[1][2][arow] + lsump[1][3][arow];
            const float sc0 = INV12 / l0;
            const float sc1 = INV12 / l1;
            const ushort_t* p0 = &Ps[0][arow * PSW + acg * 16];
            const ushort_t* p1 = &Ps[1][arow * PSW + acg * 16];
            #pragma unroll
            for (int k = 0; k < 4; ++k) {
                ushort4 u0 = *(const ushort4*)(p0 + k * 4);
                ushort4 u1 = *(const ushort4*)(p1 + k * 4);
                acc[k * 4 + 0] = fmaf(bf2f(u0.x), sc0, fmaf(bf2f(u1.x), sc1, acc[k * 4 + 0]));
                acc[k * 4 + 1] = fmaf(bf2f(u0.y), sc0, fmaf(bf2f(u1.y), sc1, acc[k * 4 + 1]));
                acc[k * 4 + 2] = fmaf(bf2f(u0.z), sc0, fmaf(bf2f(u1.z), sc1, acc[k * 4 + 2]));
                acc[k * 4 + 3] = fmaf(bf2f(u0.w), sc0, fmaf(bf2f(u1.w), sc1, acc[k * 4 + 3]));
            }
        }

        // ---- PV: wave computes head h, d-slice [ww*16, ww*16+16) ----
        {
            f32x4 oacc;
            #pragma unroll
            for (int r = 0; r < 4; ++r) oacc[r] = 0.f;
            const ushort_t* vrow = vhead + (size_t)(hq / 2 + ww * 16 + lr) * SEQ + jbase;
            for (int ci = 0; ci < nch; ++ci) {
                const int tok0 = ci * 64;
                #pragma unroll
                for (int s2 = 0; s2 < 2; ++s2) {
                    bf16x8 pa = *(const bf16x8*)&Ps[hg][lr * PSW + tok0 + s2 * 32 + quad * 8];
                    bf16x8 vf = *(const bf16x8*)(vrow + tok0 + s2 * 32 + quad * 8);
                    oacc = __builtin_amdgcn_mfma_f32_16x16x32_bf16(pa, vf, oacc, 0, 0, 0);
                }
            }
            float lr4[4];
            #pragma unroll
            for (int r = 0; r < 4; ++r)
                lr4[r] = lsump[hg][0][quad * 4 + r] + lsump[hg][1][quad * 4 + r] +
                         lsump[hg][2][quad * 4 + r] + lsump[hg][3][quad * 4 + r];
            #pragma unroll
            for (int r = 0; r < 4; ++r) {
                const int row = iq0 + quad * 4 + r;
                values[(size_t)(b * SEQ + row) * EDIM + h * 64 + ww * 16 + lr] =
                    f2bf(oacc[r] / lr4[r]);
            }
        }
        __syncthreads();   // Ps/lsump reuse next head pair
    }

    // ---- write attn_mean ----
    if (acg * 16 < span) {
        float* dst = attn_out + ((size_t)b * SEQ + iq0 + arow) * SEQ + jbase + acg * 16;
        #pragma unroll
        for (int k = 0; k < 4; ++k) {
            float4 v = { acc[k * 4 + 0], acc[k * 4 + 1], acc[k * 4 + 2], acc[k * 4 + 3] };
            *(float4*)(dst + k * 4) = v;
        }
    }
    {
        const int c4lo = jbase >> 2;
        const int c4hi = (jbase + span) >> 2;
        const float4 z = {0.f, 0.f, 0.f, 0.f};
        for (int f = tid; f < 16 * 512; f += 512) {
            const int i  = f >> 9;
            const int c4 = f & 511;
            if (c4 < c4lo || c4 >= c4hi)
                *(float4*)(attn_out + ((size_t)b * SEQ + iq0 + i) * SEQ + c4 * 4) = z;
        }
    }
}

extern "C" void kernel_launch(void* const* d_in, const int* in_sizes, int n_in,
                              void* d_out, int out_size, void* d_ws, size_t ws_size,
                              hipStream_t stream) {
    const float* x      = (const float*)d_in[0];
    const int*   pad    = (const int*)d_in[1];
    const float* mmask  = (const float*)d_in[2];
    const float* qkv_w  = (const float*)d_in[3];
    const float* qkv_b  = (const float*)d_in[4];
    const float* o_w    = (const float*)d_in[5];
    const float* o_b    = (const float*)d_in[6];

    float* out_o    = (float*)d_out;
    float* out_attn = out_o + (size_t)NB * SEQ * EDIM;

    ushort_t* qk     = (ushort_t*)d_ws;                       // NB*SEQ*1536
    ushort_t* vt     = qk + (size_t)NB * SEQ * QKW;           // NB*NH*64*SEQ
    ushort_t* xb     = vt + (size_t)NB * NH * 64 * SEQ;       // x bf16
    ushort_t* values = xb;                                    // alias (after GEMM1)
    ushort_t* wqkvb  = xb + (size_t)NB * SEQ * DIN;
    ushort_t* wob    = wqkvb + (size_t)QKVN * DIN;
    int*      wszp   = (int*)(wob + (size_t)EDIM * EDIM);
    int*      flags  = wszp + 4;

    hipMemsetAsync(flags, 0, (size_t)NB * 128 * 32 * sizeof(int), stream);

    wsz_kernel<<<NB, 256, 0, stream>>>(pad, wszp);
    flag_kernel<<<dim3(8, 128, NB), 256, 0, stream>>>(mmask, wszp, flags);

    const int nx = NB * SEQ * DIN / 4, nw1 = QKVN * DIN / 4, nw2 = EDIM * EDIM / 4;
    cvt_kernel<<<(nx  + 255) / 256, 256, 0, stream>>>(x,     xb,    nx);
    cvt_kernel<<<(nw1 + 255) / 256, 256, 0, stream>>>(qkv_w, wqkvb, nw1);
    cvt_kernel<<<(nw2 + 255) / 256, 256, 0, stream>>>(o_w,   wob,   nw2);

    mfma_gemm128<1><<<dim3(QKVN / 128, (NB * SEQ) / 128), 256, 0, stream>>>(
        xb, wqkvb, qkv_b, nullptr, qk, vt, QKVN, DIN);

    attn_kernel<<<512, 512, 0, stream>>>(
        qk, vt, mmask, wszp, flags, values, out_attn);

    mfma_gemm128<0><<<dim3(EDIM / 128, (NB * SEQ) / 128), 256, 0, stream>>>(
        values, wob, o_b, out_o, nullptr, nullptr, EDIM, EDIM);
}